// Round 1
// baseline (55.244 us; speedup 1.0000x reference)
//
#include <hip/hip_runtime.h>

#define HALF 16
#define PS   33            // patch side = 2*HALF+1
#define KOF  (PS * PS)     // 1089 offsets per landmark
#define IMW  512
#define IMH  512

__global__ __launch_bounds__(256)
void lm_scatter_kernel(const float* __restrict__ landmarks,  // [B, L, 2]
                       float* __restrict__ out,              // [B, IMH*IMW]
                       int L)
{
    const int bl = blockIdx.x;            // = b*L + l
    const int b  = bl / L;

    // landmark coords: [.x = coord0 (fast/column axis), .y = coord1 (row axis)]
    const float2 lm = reinterpret_cast<const float2*>(landmarks)[bl];

    float x0 = fminf(fmaxf(lm.x, (float)HALF), (float)(IMW - 1 - HALF));
    float x1 = fminf(fmaxf(lm.y, (float)HALF), (float)(IMH - 1 - HALF));
    float f0 = floorf(x0);
    float f1 = floorf(x1);
    int   i0 = (int)f0;
    int   i1 = (int)f1;
    float d0 = x0 - f0;     // subpixel residual, coord0
    float d1 = x1 - f1;     // subpixel residual, coord1

    float* base = out + (size_t)b * (IMH * IMW) + (size_t)i1 * IMW + i0;

    // k enumerates the 33x33 patch; a (fast, 0..32) -> offset o0 (contiguous in
    // memory), c (0..32) -> offset o1 (row stride IMW). Consecutive lanes hit
    // consecutive addresses within each patch row.
    for (int k = threadIdx.x; k < KOF; k += 256) {
        int c = k / PS;
        int a = k - c * PS;
        int o0 = a - HALF;
        int o1 = c - HALF;
        float s0 = (float)o0 - d0;
        float s1 = (float)o1 - d1;
        float dist2 = s0 * s0 + s1 * s1 + 1e-6f;
        float val = 1.0f / (1.0f + sqrtf(dist2));
        atomicAdd(base + o1 * IMW + o0, val);
    }
}

extern "C" void kernel_launch(void* const* d_in, const int* in_sizes, int n_in,
                              void* d_out, int out_size, void* d_ws, size_t ws_size,
                              hipStream_t stream)
{
    // d_in[0] = img  (UNUSED by the reference)
    // d_in[1] = landmarks [B, L, 2] float32
    const float* landmarks = (const float*)d_in[1];
    float* out = (float*)d_out;

    const int B = out_size / (IMH * IMW);        // 64
    const int L = in_sizes[1] / (2 * B);         // 106

    // Output is accumulated into — must start from zeros every call.
    hipMemsetAsync(d_out, 0, (size_t)out_size * sizeof(float), stream);

    lm_scatter_kernel<<<B * L, 256, 0, stream>>>(landmarks, out, L);
}

// Round 2
// 24.134 us; speedup vs baseline: 2.2890x; 2.2890x over previous
//
#include <hip/hip_runtime.h>

#define HALF 16
#define IMW  512
#define IMH  512
#define TILE 32
#define TPA  16            // tiles per axis = 512/32
#define TPI  256           // tiles per image
#define MAXL 256           // LDS list capacity (>= L, overflow impossible)

// One block per 32x32 output tile. Scans the image's landmarks (L2-resident,
// 848 B) into an LDS list of those whose 33x33 patch intersects this tile
// (patch width 33 > 32 => exactly 2x2 tiles per landmark), then each thread
// accumulates 4 pixels (same column, rows +0/+8/+16/+24) in registers and
// writes each output pixel exactly once. No atomics, no output memset.
__global__ __launch_bounds__(256)
void lm_gather_kernel(const float* __restrict__ landmarks,  // [B, L, 2]
                      float* __restrict__ out,              // [B, IMH*IMW]
                      int L)
{
    __shared__ float2 slm[MAXL];
    __shared__ int sn;

    const int t    = threadIdx.x;
    const int bx   = blockIdx.x;
    const int b    = bx >> 8;           // image index (TPI == 256)
    const int tile = bx & (TPI - 1);
    const int tx   = tile & (TPA - 1);
    const int ty   = tile >> 4;

    if (t == 0) sn = 0;
    __syncthreads();

    // Phase 1: gather this tile's landmarks into LDS.
    const float2* lmb = reinterpret_cast<const float2*>(landmarks) + (size_t)b * L;
    for (int j = t; j < L; j += 256) {
        float2 lm = lmb[j];
        float x0 = fminf(fmaxf(lm.x, (float)HALF), (float)(IMW - 1 - HALF));
        float x1 = fminf(fmaxf(lm.y, (float)HALF), (float)(IMH - 1 - HALF));
        int i0 = (int)x0;               // coords >= 16 > 0, trunc == floor
        int i1 = (int)x1;
        int tx0 = (i0 - HALF) >> 5;     // patch spans tiles {tx0, tx0+1} x {ty0, ty0+1}
        int ty0 = (i1 - HALF) >> 5;
        if ((unsigned)(tx - tx0) <= 1u && (unsigned)(ty - ty0) <= 1u) {
            int pos = atomicAdd(&sn, 1);   // LDS atomic
            if (pos < MAXL) slm[pos] = make_float2(x0, x1);
        }
    }
    __syncthreads();
    const int n = min(sn, MAXL);

    // Phase 2: accumulate 4 pixels per thread in registers.
    const int   px  = tx * TILE + (t & 31);
    const int   py0 = ty * TILE + (t >> 5);   // rows py0 + {0,8,16,24}
    const float fpx = (float)px;

    float acc[4] = {0.0f, 0.0f, 0.0f, 0.0f};
    for (int j = 0; j < n; ++j) {
        float2 e = slm[j];
        int   i0   = (int)e.x;
        int   i1   = (int)e.y;
        float dx   = fpx - e.x;
        float dx2e = dx * dx + 1e-6f;
        bool  in0  = (unsigned)(px - i0 + HALF) <= (unsigned)(2 * HALF);
        #pragma unroll
        for (int r = 0; r < 4; ++r) {
            int   py  = py0 + 8 * r;
            float dy  = (float)py - e.y;
            bool  in1 = (unsigned)(py - i1 + HALF) <= (unsigned)(2 * HALF);
            // val = 1/(1+sqrt(d2)); hw sqrt+rcp are ~1 ulp, threshold is 4.3e-2
            float v = __builtin_amdgcn_rcpf(1.0f + __builtin_amdgcn_sqrtf(dx2e + dy * dy));
            acc[r] += (in0 && in1) ? v : 0.0f;
        }
    }

    // Phase 3: one coalesced store per row-group; every pixel written once.
    float* op = out + (size_t)b * (IMH * IMW) + (size_t)py0 * IMW + px;
    #pragma unroll
    for (int r = 0; r < 4; ++r)
        op[(size_t)r * 8 * IMW] = acc[r];
}

extern "C" void kernel_launch(void* const* d_in, const int* in_sizes, int n_in,
                              void* d_out, int out_size, void* d_ws, size_t ws_size,
                              hipStream_t stream)
{
    // d_in[0] = img (unused by the reference); d_in[1] = landmarks [B, L, 2] f32
    const float* landmarks = (const float*)d_in[1];
    float* out = (float*)d_out;

    const int B = out_size / (IMH * IMW);   // 64
    const int L = in_sizes[1] / (2 * B);    // 106

    lm_gather_kernel<<<B * TPI, 256, 0, stream>>>(landmarks, out, L);
}

// Round 4
// 23.685 us; speedup vs baseline: 2.3324x; 1.0189x over previous
//
#include <hip/hip_runtime.h>

#define HALF 16
#define IMW  512
#define IMH  512
#define TILE 32
#define TPA  16            // tiles per axis = 512/32
#define TPI  256           // tiles per image
#define MAXL 256           // LDS list capacity (>= L, overflow impossible)

typedef float f32x4 __attribute__((ext_vector_type(4)));  // native vector: ok for nontemporal builtin

// One block per 32x32 output tile. Phase 1 scans the image's 106 landmarks
// (848 B, L2-resident) into an LDS list of those whose 33x33 patch intersects
// this tile (patch 33 > 32 => exactly 2x2 tiles per landmark). Phase 2: each
// thread owns 4 CONTIGUOUS pixels of one row (t>>3 = row, (t&7)*4 = col base),
// so dy^2+eps hoists per landmark and the store is a single aligned float4
// (16 B/lane = 1 KiB/wave). Output written exactly once -> nontemporal.
__global__ __launch_bounds__(256)
void lm_gather_kernel(const float* __restrict__ landmarks,  // [B, L, 2]
                      float* __restrict__ out,              // [B, IMH*IMW]
                      int L)
{
    __shared__ float2 slm[MAXL];
    __shared__ int sn;

    const int t    = threadIdx.x;
    const int bx   = blockIdx.x;
    const int b    = bx >> 8;           // image index (TPI == 256)
    const int tile = bx & (TPI - 1);
    const int tx   = tile & (TPA - 1);
    const int ty   = tile >> 4;

    if (t == 0) sn = 0;
    __syncthreads();

    // Phase 1: gather this tile's landmarks into LDS.
    const float2* lmb = reinterpret_cast<const float2*>(landmarks) + (size_t)b * L;
    for (int j = t; j < L; j += 256) {
        float2 lm = lmb[j];
        float x0 = fminf(fmaxf(lm.x, (float)HALF), (float)(IMW - 1 - HALF));
        float x1 = fminf(fmaxf(lm.y, (float)HALF), (float)(IMH - 1 - HALF));
        int i0 = (int)x0;               // coords >= 16 > 0, trunc == floor
        int i1 = (int)x1;
        int tx0 = (i0 - HALF) >> 5;     // patch spans tiles {tx0,tx0+1} x {ty0,ty0+1}
        int ty0 = (i1 - HALF) >> 5;
        if ((unsigned)(tx - tx0) <= 1u && (unsigned)(ty - ty0) <= 1u) {
            int pos = atomicAdd(&sn, 1);   // LDS atomic
            if (pos < MAXL) slm[pos] = make_float2(x0, x1);
        }
    }
    __syncthreads();
    const int n = min(sn, MAXL);

    // Phase 2: 4 contiguous pixels per thread, one row.
    const int py  = ty * TILE + (t >> 3);
    const int px0 = tx * TILE + (t & 7) * 4;
    const float fpy = (float)py;

    float acc[4] = {0.0f, 0.0f, 0.0f, 0.0f};
    for (int j = 0; j < n; ++j) {
        float2 e = slm[j];
        int   i0   = (int)e.x;
        int   i1   = (int)e.y;
        float dy   = fpy - e.y;
        float dy2e = dy * dy + 1e-6f;
        bool  in1  = (unsigned)(py - i1 + HALF) <= (unsigned)(2 * HALF);
        #pragma unroll
        for (int c = 0; c < 4; ++c) {
            int   px  = px0 + c;
            float dx  = (float)px - e.x;
            bool  in0 = (unsigned)(px - i0 + HALF) <= (unsigned)(2 * HALF);
            // val = 1/(1+sqrt(d2)); hw sqrt+rcp ~1 ulp, threshold 4.3e-2
            float v = __builtin_amdgcn_rcpf(1.0f + __builtin_amdgcn_sqrtf(dx * dx + dy2e));
            acc[c] += (in0 && in1) ? v : 0.0f;
        }
    }

    // Phase 3: single aligned 16B nontemporal store per thread.
    float* op = out + (size_t)b * (IMH * IMW) + (size_t)py * IMW + px0;
    f32x4 v4 = { acc[0], acc[1], acc[2], acc[3] };
    __builtin_nontemporal_store(v4, reinterpret_cast<f32x4*>(op));
}

extern "C" void kernel_launch(void* const* d_in, const int* in_sizes, int n_in,
                              void* d_out, int out_size, void* d_ws, size_t ws_size,
                              hipStream_t stream)
{
    // d_in[0] = img (unused by the reference); d_in[1] = landmarks [B, L, 2] f32
    const float* landmarks = (const float*)d_in[1];
    float* out = (float*)d_out;

    const int B = out_size / (IMH * IMW);   // 64
    const int L = in_sizes[1] / (2 * B);    // 106

    lm_gather_kernel<<<B * TPI, 256, 0, stream>>>(landmarks, out, L);
}